// Round 1
// baseline (306.117 us; speedup 1.0000x reference)
//
#include <hip/hip_runtime.h>

typedef int v4i __attribute__((ext_vector_type(4)));

#define QMAX 127.0f

// ---- workspace layout ----
// xq : int8 NHWC padded  [16][66][66][320]  = 22,302,720 B   (offset 0)
// wq : int8              [9][320][320]      =    921,600 B   (offset 22,302,720)
// bi : float             [320]              =      1,280 B   (offset 23,224,320)
#define XQ_BYTES 22302720
#define WQ_BYTES 921600

__device__ __forceinline__ float clampf(float v, float lo, float hi) {
    return fminf(fmaxf(v, lo), hi);
}

// ---------------------------------------------------------------------------
// x (NCHW f32) -> quantize -> xq (padded NHWC int8). Halo is pre-zeroed by
// memset. One block per (ci_tile of 64, h, b). LDS transpose, strides chosen
// so all phases are <=2-way bank conflicts (free on gfx950).
// ---------------------------------------------------------------------------
__global__ __launch_bounds__(256) void quant_x_kernel(
    const float* __restrict__ x, const float* __restrict__ step_p,
    char* __restrict__ xq)
{
    __shared__ float F[64 * 65];   // [ci][w], stride 65 floats
    const int t   = threadIdx.x;
    const int ci0 = blockIdx.x * 64;
    const int h   = blockIdx.y;
    const int b   = blockIdx.z;
    const float step = *step_p;

    // phase 1: coalesced read of 64 ci-rows x 64 w floats
    {
        const int r = t >> 2, q = t & 3;                 // r: ci row, q: 16-float chunk
        const float* src = x + (((size_t)(b * 320 + ci0 + r) * 64 + h) * 64);
#pragma unroll
        for (int i = 0; i < 4; ++i) {
            float4 v = *(const float4*)(src + q * 16 + i * 4);
            float* dst = &F[r * 65 + q * 16 + i * 4];
            dst[0] = v.x; dst[1] = v.y; dst[2] = v.z; dst[3] = v.w;
        }
    }
    __syncthreads();

    // phase 2: each thread packs 16 ci bytes for one w pixel -> one int4 store
    {
        const int w  = t & 63;
        const int cg = t >> 6;   // 16-ci group
        int dws[4];
#pragma unroll
        for (int j = 0; j < 4; ++j) {
            int word = 0;
#pragma unroll
            for (int k2 = 0; k2 < 4; ++k2) {
                int ci = cg * 16 + j * 4 + k2;
                float v = F[ci * 65 + w];
                int xi = (int)clampf(rintf(v / step), -QMAX, QMAX);
                word |= (xi & 0xFF) << (8 * k2);
            }
            dws[j] = word;
        }
        v4i pk = { dws[0], dws[1], dws[2], dws[3] };
        size_t off = ((size_t)(b * 66 + (h + 1)) * 66 + (w + 1)) * 320 + ci0 + cg * 16;
        *(v4i*)&xq[off] = pk;
    }
}

// ---------------------------------------------------------------------------
// weight OIHW f32 -> quantize -> wq[p][co][ci] int8 (ci contiguous)
// ---------------------------------------------------------------------------
__global__ __launch_bounds__(256) void quant_w_kernel(
    const float* __restrict__ w, const float* __restrict__ step_p,
    char* __restrict__ wq)
{
    const int tid = blockIdx.x * 256 + threadIdx.x;   // 0 .. 921599
    const float step = *step_p;
    const int p   = tid / 102400;
    const int rem = tid - p * 102400;
    const int co  = rem / 320;
    const int ci  = rem - co * 320;
    float v = w[(size_t)co * 2880 + ci * 9 + p];
    int q = (int)clampf(rintf(v / step), -QMAX, QMAX);
    wq[tid] = (char)q;
}

// ---------------------------------------------------------------------------
// bias -> integer-scale epilogue constant b_int8[co] (float, integer-valued)
// exact reference op order: ((b_deq * shift) * x_scale) * w_scale
// ---------------------------------------------------------------------------
__global__ void quant_b_kernel(
    const float* __restrict__ bias, const float* __restrict__ step_b_p,
    const float* __restrict__ step_x_p, const float* __restrict__ step_w_p,
    const float* __restrict__ shift_p, float* __restrict__ bi)
{
    const int co = threadIdx.x;
    if (co >= 320) return;
    const float step_b = *step_b_p;
    const float xs = 1.0f / *step_x_p;
    const float ws = 1.0f / *step_w_p;
    const float shift = *shift_p;
    float b_deq = clampf(rintf(bias[co] / step_b), -QMAX, QMAX) * step_b;
    float v = ((b_deq * shift) * xs) * ws;
    bi[co] = clampf(rintf(v), -QMAX, QMAX);
}

// ---------------------------------------------------------------------------
// Implicit-GEMM conv via v_mfma_i32_16x16x64_i8.
// Grid: x = co tile (5 of 64), y = pixel tile (256 of 256 px = 4 output rows).
// Block 256 thr = 4 waves; wave computes 64co x 64px (one output row).
// K-loop: 9 filter taps x 5 ci-chunks of 64.
// ---------------------------------------------------------------------------
__global__ __launch_bounds__(256) void conv_mfma_kernel(
    const char* __restrict__ xq, const char* __restrict__ wq,
    const float* __restrict__ bi, const float* __restrict__ shift_p,
    float* __restrict__ out)
{
    __shared__ __attribute__((aligned(16))) char As[64 * 80];    // [co][ci]
    __shared__ __attribute__((aligned(16))) char Bs[256 * 80];   // [px][ci]

    const int t     = threadIdx.x;
    const int co0   = blockIdx.x * 64;
    const int ptile = blockIdx.y;        // 0..255
    const int b     = ptile >> 4;        // 16 tiles per image
    const int h0    = (ptile & 15) * 4;  // 4 output rows per tile

    const int wave = t >> 6, lane = t & 63;
    const int quad = lane >> 4, l15 = lane & 15;
    const int r  = t >> 2;               // staging row 0..63
    const int ck = (t & 3) * 16;         // staging 16B chunk

    v4i acc[4][4] = {};

    for (int p = 0; p < 9; ++p) {
        const int dh = p / 3, dw = p - dh * 3;
        const char* wqp = wq + p * 102400;
        for (int c5 = 0; c5 < 5; ++c5) {
            const int ci0 = c5 * 64;
            // stage A: 64co x 64ci
            *(v4i*)&As[r * 80 + ck] =
                *(const v4i*)&wqp[(co0 + r) * 320 + ci0 + ck];
            // stage B: 256px x 64ci (4 output rows, shifted by (dh,dw))
#pragma unroll
            for (int s = 0; s < 4; ++s) {
                size_t goff = ((size_t)(b * 66 + (h0 + s + dh)) * 66 + (r + dw)) * 320
                              + ci0 + ck;
                *(v4i*)&Bs[(s * 64 + r) * 80 + ck] = *(const v4i*)&xq[goff];
            }
            __syncthreads();

            v4i a[4], bf[4];
#pragma unroll
            for (int i = 0; i < 4; ++i)
                a[i] = *(const v4i*)&As[(i * 16 + l15) * 80 + quad * 16];
#pragma unroll
            for (int i = 0; i < 4; ++i)
                bf[i] = *(const v4i*)&Bs[(wave * 64 + i * 16 + l15) * 80 + quad * 16];
#pragma unroll
            for (int cs = 0; cs < 4; ++cs)
#pragma unroll
                for (int ns = 0; ns < 4; ++ns)
                    acc[cs][ns] = __builtin_amdgcn_mfma_i32_16x16x64_i8(
                        a[cs], bf[ns], acc[cs][ns], 0, 0, 0);
            __syncthreads();
        }
    }

    // epilogue: y_shift = clip(rint(y*shift)); out = clip(y_shift + b_int8)
    const float shift = *shift_p;
    const int h = h0 + wave;             // wave owns one output row
#pragma unroll
    for (int cs = 0; cs < 4; ++cs) {
#pragma unroll
        for (int reg = 0; reg < 4; ++reg) {
            const int co = co0 + cs * 16 + quad * 4 + reg;
            const float bv = bi[co];
            float* orow = out + (((size_t)(b * 320 + co) * 64) + h) * 64;
#pragma unroll
            for (int ns = 0; ns < 4; ++ns) {
                float y  = (float)acc[cs][ns][reg];
                float ys = clampf(rintf(y * shift), -QMAX, QMAX);
                float o  = clampf(ys + bv, -QMAX, QMAX);
                orow[ns * 16 + l15] = o;
            }
        }
    }
}

extern "C" void kernel_launch(void* const* d_in, const int* in_sizes, int n_in,
                              void* d_out, int out_size, void* d_ws, size_t ws_size,
                              hipStream_t stream) {
    const float* x      = (const float*)d_in[0];
    const float* w      = (const float*)d_in[1];
    const float* bias   = (const float*)d_in[2];
    const float* step_x = (const float*)d_in[3];
    const float* step_w = (const float*)d_in[4];
    const float* step_b = (const float*)d_in[5];
    const float* shift  = (const float*)d_in[6];
    float* out = (float*)d_out;

    char*  xq = (char*)d_ws;
    char*  wq = xq + XQ_BYTES;
    float* bi = (float*)(wq + WQ_BYTES);

    // zero padded NHWC buffer (halo must be 0; ws is poisoned each launch)
    hipMemsetAsync(xq, 0, XQ_BYTES, stream);

    quant_x_kernel<<<dim3(5, 64, 16), 256, 0, stream>>>(x, step_x, xq);
    quant_w_kernel<<<3600, 256, 0, stream>>>(w, step_w, wq);
    quant_b_kernel<<<1, 320, 0, stream>>>(bias, step_b, step_x, step_w, shift, bi);
    conv_mfma_kernel<<<dim3(5, 256), 256, 0, stream>>>(xq, wq, bi, shift, out);
}

// Round 2
// 238.428 us; speedup vs baseline: 1.2839x; 1.2839x over previous
//
#include <hip/hip_runtime.h>

typedef int v4i __attribute__((ext_vector_type(4)));

#define QMAX 127.0f

// ---- workspace layout ----
// xq  : int8 NHWC padded  [16][66][66][320]          = 22,302,720 B (offset 0)
// wq2 : int8 fragment-order [9][5][20][64lane][16B]  =    921,600 B
// bi  : float [320]
#define XQ_BYTES 22302720
#define WQ_BYTES 921600

__device__ __forceinline__ float clampf(float v, float lo, float hi) {
    return fminf(fmaxf(v, lo), hi);
}

__device__ __forceinline__ void gload_lds16(const char* g, char* l) {
    __builtin_amdgcn_global_load_lds(
        (const __attribute__((address_space(1))) void*)g,
        (__attribute__((address_space(3))) void*)l, 16, 0, 0);
}

// ---------------------------------------------------------------------------
// x (NCHW f32) -> quantize -> xq (padded NHWC int8), interior only.
// ---------------------------------------------------------------------------
__global__ __launch_bounds__(256) void quant_x_kernel(
    const float* __restrict__ x, const float* __restrict__ step_p,
    char* __restrict__ xq)
{
    __shared__ float F[64 * 65];   // [ci][w], stride 65 floats
    const int t   = threadIdx.x;
    const int ci0 = blockIdx.x * 64;
    const int h   = blockIdx.y;
    const int b   = blockIdx.z;
    const float step = *step_p;

    // phase 1: coalesced read of 64 ci-rows x 64 w floats
    {
        const int r = t >> 2, q = t & 3;
        const float* src = x + (((size_t)(b * 320 + ci0 + r) * 64 + h) * 64);
#pragma unroll
        for (int i = 0; i < 4; ++i) {
            float4 v = *(const float4*)(src + q * 16 + i * 4);
            float* dst = &F[r * 65 + q * 16 + i * 4];
            dst[0] = v.x; dst[1] = v.y; dst[2] = v.z; dst[3] = v.w;
        }
    }
    __syncthreads();

    // phase 2: each thread packs 16 ci bytes for one w pixel -> one 16B store
    {
        const int w  = t & 63;
        const int cg = t >> 6;
        int dws[4];
#pragma unroll
        for (int j = 0; j < 4; ++j) {
            int word = 0;
#pragma unroll
            for (int k2 = 0; k2 < 4; ++k2) {
                int ci = cg * 16 + j * 4 + k2;
                float v = F[ci * 65 + w];
                int xi = (int)clampf(rintf(v / step), -QMAX, QMAX);
                word |= (xi & 0xFF) << (8 * k2);
            }
            dws[j] = word;
        }
        v4i pk = { dws[0], dws[1], dws[2], dws[3] };
        size_t off = ((size_t)(b * 66 + (h + 1)) * 66 + (w + 1)) * 320 + ci0 + cg * 16;
        *(v4i*)&xq[off] = pk;
    }
}

// ---------------------------------------------------------------------------
// zero the padded halo (rows 0,65 all cols; cols 0,65 rows 1..64)
// 16 b * 260 px * 20 chunks = 83,200 threads
// ---------------------------------------------------------------------------
__global__ __launch_bounds__(256) void halo_kernel(char* __restrict__ xq)
{
    int tid = blockIdx.x * 256 + threadIdx.x;
    if (tid >= 83200) return;
    int b = tid / 5200;
    int r = tid - b * 5200;
    int px = r / 20;
    int ck = (r - px * 20) * 16;
    int row, col;
    if (px < 66)       { row = 0;  col = px; }
    else if (px < 132) { row = 65; col = px - 66; }
    else { int e = px - 132; row = 1 + (e >> 1); col = (e & 1) * 65; }
    size_t off = ((size_t)(b * 66 + row) * 66 + col) * 320 + ck;
    v4i z = {0, 0, 0, 0};
    *(v4i*)&xq[off] = z;
}

// ---------------------------------------------------------------------------
// weight OIHW f32 -> quantize -> wq2 fragment-order:
// off(p,co,ci) = (((p*5 + ci/64)*20 + co/16)*64 + (co&15) + ((ci>>4)&3)*16)*16 + (ci&15)
// One thread per (co,ci): reads 9 contiguous floats, scatters 9 bytes.
// ---------------------------------------------------------------------------
__global__ __launch_bounds__(256) void quant_w_kernel(
    const float* __restrict__ w, const float* __restrict__ step_p,
    char* __restrict__ wq2)
{
    int tid = blockIdx.x * 256 + threadIdx.x;   // 0..102399
    const float step = *step_p;
    int co = tid / 320;
    int ci = tid - co * 320;
    int c5 = ci >> 6, quad = (ci >> 4) & 3, j = ci & 15;
    int cog = co >> 4, l15 = co & 15;
    const float* src = w + (size_t)co * 2880 + ci * 9;
    size_t base = ((size_t)(c5 * 20 + cog) * 64 + (l15 + quad * 16)) * 16 + j;
#pragma unroll
    for (int p = 0; p < 9; ++p) {
        float v = src[p];
        int q = (int)clampf(rintf(v / step), -QMAX, QMAX);
        wq2[p * 102400 + base] = (char)q;
    }
}

// ---------------------------------------------------------------------------
// bias epilogue constant (exact reference op order)
// ---------------------------------------------------------------------------
__global__ void quant_b_kernel(
    const float* __restrict__ bias, const float* __restrict__ step_b_p,
    const float* __restrict__ step_x_p, const float* __restrict__ step_w_p,
    const float* __restrict__ shift_p, float* __restrict__ bi)
{
    const int co = threadIdx.x;
    if (co >= 320) return;
    const float step_b = *step_b_p;
    const float xs = 1.0f / *step_x_p;
    const float ws = 1.0f / *step_w_p;
    const float shift = *shift_p;
    float b_deq = clampf(rintf(bias[co] / step_b), -QMAX, QMAX) * step_b;
    float v = ((b_deq * shift) * xs) * ws;
    bi[co] = clampf(rintf(v), -QMAX, QMAX);
}

// ---------------------------------------------------------------------------
// Implicit-GEMM conv, v_mfma_i32_16x16x64_i8.
// Grid (5 co-tiles, 256 pixel-tiles). Block 256 = 4 waves; wave = 64co x 64px
// (one output row). Per ci-chunk stage: B = 6 rows x 66 px x 64 ci (swizzled),
// A = 9 taps x 64co x 64ci in fragment order via global_load_lds. All 9 taps
// computed per barrier pair (144 MFMA/wave between syncs).
// ---------------------------------------------------------------------------
__global__ __launch_bounds__(256) void conv_mfma_kernel(
    const char* __restrict__ xq, const char* __restrict__ wq2,
    const float* __restrict__ bi, const float* __restrict__ shift_p,
    float* __restrict__ out)
{
    __shared__ __attribute__((aligned(16))) char A_lds[36864]; // [p][cs][lane][16]
    __shared__ __attribute__((aligned(16))) char B_lds[25344]; // [px][64] xor-swizzled

    const int t   = threadIdx.x;
    const int bx  = blockIdx.x;
    const int co0 = bx * 64;
    const int ptile = blockIdx.y;
    const int b  = ptile >> 4;
    const int h0 = (ptile & 15) * 4;

    const int wave = t >> 6, lane = t & 63;
    const int quad = lane >> 4, l15 = lane & 15;

    // padded rows h0..h0+5, cols 0..65 : base of the 6-row window
    const char* xbase = xq + ((size_t)(b * 66 + h0) * 66) * 320;

    v4i acc[4][4] = {};

    for (int c5 = 0; c5 < 5; ++c5) {
        const int ci0 = c5 * 64;

        // --- stage B: 396 px x 4 chunks = 1584 16B chunks, xor-swizzled ---
        for (int c = t; c < 1584; c += 256) {
            int px = c >> 2;
            int ck = (c & 3) << 4;
            v4i v = *(const v4i*)&xbase[(size_t)px * 320 + ci0 + ck];
            *(v4i*)&B_lds[px * 64 + (ck ^ ((((px >> 1) & 3)) << 4))] = v;
        }

        // --- stage A: 9 taps, wave stages its cs=wave section, 1KB DMA each ---
        {
            const char* g = wq2 + ((size_t)(c5 * 20 + bx * 4 + wave)) * 1024
                            + (size_t)lane * 16;
            char* l = &A_lds[wave * 1024];
#pragma unroll
            for (int p = 0; p < 9; ++p)
                gload_lds16(g + (size_t)p * 102400, l + p * 4096);
        }

        __syncthreads();

#pragma unroll
        for (int p = 0; p < 9; ++p) {
            const int dh = p / 3, dw = p - dh * 3;
            v4i a[4], bf[4];
#pragma unroll
            for (int cs = 0; cs < 4; ++cs)
                a[cs] = *(const v4i*)&A_lds[(p * 4 + cs) * 1024 + lane * 16];
#pragma unroll
            for (int i = 0; i < 4; ++i) {
                int px = (wave + dh) * 66 + i * 16 + l15 + dw;
                bf[i] = *(const v4i*)&B_lds[px * 64 +
                         ((quad << 4) ^ (((px >> 1) & 3) << 4))];
            }
#pragma unroll
            for (int cs = 0; cs < 4; ++cs)
#pragma unroll
                for (int i = 0; i < 4; ++i)
                    acc[cs][i] = __builtin_amdgcn_mfma_i32_16x16x64_i8(
                        a[cs], bf[i], acc[cs][i], 0, 0, 0);
        }

        __syncthreads();
    }

    // epilogue: y_shift = clip(rint(y*shift)); out = clip(y_shift + b_int8)
    const float shift = *shift_p;
    const int h = h0 + wave;
#pragma unroll
    for (int cs = 0; cs < 4; ++cs) {
#pragma unroll
        for (int reg = 0; reg < 4; ++reg) {
            const int co = co0 + cs * 16 + quad * 4 + reg;
            const float bv = bi[co];
            float* orow = out + (((size_t)(b * 320 + co) * 64) + h) * 64;
#pragma unroll
            for (int i = 0; i < 4; ++i) {
                float y  = (float)acc[cs][i][reg];
                float ys = clampf(rintf(y * shift), -QMAX, QMAX);
                orow[i * 16 + l15] = clampf(ys + bv, -QMAX, QMAX);
            }
        }
    }
}

extern "C" void kernel_launch(void* const* d_in, const int* in_sizes, int n_in,
                              void* d_out, int out_size, void* d_ws, size_t ws_size,
                              hipStream_t stream) {
    const float* x      = (const float*)d_in[0];
    const float* w      = (const float*)d_in[1];
    const float* bias   = (const float*)d_in[2];
    const float* step_x = (const float*)d_in[3];
    const float* step_w = (const float*)d_in[4];
    const float* step_b = (const float*)d_in[5];
    const float* shift  = (const float*)d_in[6];
    float* out = (float*)d_out;

    char*  xq  = (char*)d_ws;
    char*  wq2 = xq + XQ_BYTES;
    float* bi  = (float*)(wq2 + WQ_BYTES);

    quant_x_kernel<<<dim3(5, 64, 16), 256, 0, stream>>>(x, step_x, xq);
    halo_kernel<<<325, 256, 0, stream>>>(xq);
    quant_w_kernel<<<400, 256, 0, stream>>>(w, step_w, wq2);
    quant_b_kernel<<<1, 320, 0, stream>>>(bias, step_b, step_x, step_w, shift, bi);
    conv_mfma_kernel<<<dim3(5, 256), 256, 0, stream>>>(xq, wq2, bi, shift, out);
}

// Round 3
// 236.691 us; speedup vs baseline: 1.2933x; 1.0073x over previous
//
#include <hip/hip_runtime.h>

typedef int v4i __attribute__((ext_vector_type(4)));

#define QMAX 127.0f

// ---- workspace layout ----
// xq  : int8 NHWC padded  [16][66][66][320]          = 22,302,720 B (offset 0)
// wq2 : int8 fragment-order [9][5][20cog][64lane][16]=    921,600 B
// bi  : float [320]
#define XQ_BYTES 22302720
#define WQ_BYTES 921600

__device__ __forceinline__ float clampf(float v, float lo, float hi) {
    return fminf(fmaxf(v, lo), hi);
}

__device__ __forceinline__ void gload_lds16(const char* g, char* l) {
    __builtin_amdgcn_global_load_lds(
        (const __attribute__((address_space(1))) void*)g,
        (__attribute__((address_space(3))) void*)l, 16, 0, 0);
}

__device__ __forceinline__ v4i mfma_i8(v4i a, v4i b, v4i c) {
    return __builtin_amdgcn_mfma_i32_16x16x64_i8(a, b, c, 0, 0, 0);
}

// ---------------------------------------------------------------------------
// x (NCHW f32) -> quantize -> xq (padded NHWC int8), interior only.
// Phase-1 coalescing: 16 consecutive lanes read one contiguous 256B ci-row.
// ---------------------------------------------------------------------------
__global__ __launch_bounds__(256) void quant_x_kernel(
    const float* __restrict__ x, const float* __restrict__ step_p,
    char* __restrict__ xq)
{
    __shared__ float F[64 * 65];   // [ci][w], stride 65 floats
    const int t   = threadIdx.x;
    const int ci0 = blockIdx.x * 64;
    const int h   = blockIdx.y;
    const int b   = blockIdx.z;
    const float step = *step_p;

    // phase 1: 64 ci-rows x 64 w floats; wave = 4 full contiguous rows
    {
        const int r = t >> 4, c = (t & 15) * 4;
        const float* src = x + (((size_t)(b * 320 + ci0) * 64 + h) * 64);
#pragma unroll
        for (int i = 0; i < 4; ++i) {
            const int row = r + i * 16;
            float4 v = *(const float4*)(src + (size_t)row * 4096 + c);
            *(float4*)&F[row * 65 + c] = v;
        }
    }
    __syncthreads();

    // phase 2: each thread packs 16 ci bytes for one w pixel -> one 16B store
    {
        const int w  = t & 63;
        const int cg = t >> 6;
        int dws[4];
#pragma unroll
        for (int j = 0; j < 4; ++j) {
            int word = 0;
#pragma unroll
            for (int k2 = 0; k2 < 4; ++k2) {
                int ci = cg * 16 + j * 4 + k2;
                float v = F[ci * 65 + w];
                int xi = (int)clampf(rintf(v / step), -QMAX, QMAX);
                word |= (xi & 0xFF) << (8 * k2);
            }
            dws[j] = word;
        }
        v4i pk = { dws[0], dws[1], dws[2], dws[3] };
        size_t off = ((size_t)(b * 66 + (h + 1)) * 66 + (w + 1)) * 320 + ci0 + cg * 16;
        *(v4i*)&xq[off] = pk;
    }
}

// ---------------------------------------------------------------------------
// Fused prep: [0,3600) wq2 quantize (coalesced writes), [3600,3925) halo zero,
// [3925] bias constant.
// wq2 layout: [p][c5][cogG 0..19][lane 0..63][16], where the byte at
// (p,c5,cogG,lane,j) = w_int8(co = cogG*16 + (lane&15), ci = c5*64 + (lane>>4)*16 + j)
// ---------------------------------------------------------------------------
__global__ __launch_bounds__(256) void prep_kernel(
    const float* __restrict__ w, const float* __restrict__ bias,
    const float* __restrict__ step_w_p, const float* __restrict__ step_b_p,
    const float* __restrict__ step_x_p, const float* __restrict__ shift_p,
    char* __restrict__ wq2, char* __restrict__ xq, float* __restrict__ bi)
{
    const int bid = blockIdx.x;
    if (bid < 3600) {
        const int tid = bid * 256 + threadIdx.x;   // byte index into wq2
        const float step = *step_w_p;
        const int p    = tid / 102400;
        const int r    = tid - p * 102400;
        const int c5   = r / 20480;
        const int r2   = r - c5 * 20480;
        const int cog  = r2 >> 10;
        const int r3   = r2 & 1023;
        const int lane = r3 >> 4, j = r3 & 15;
        const int co = cog * 16 + (lane & 15);
        const int ci = c5 * 64 + (lane >> 4) * 16 + j;
        float v = w[(size_t)co * 2880 + ci * 9 + p];
        int q = (int)clampf(rintf(v / step), -QMAX, QMAX);
        wq2[tid] = (char)q;
    } else if (bid < 3925) {
        int tid = (bid - 3600) * 256 + threadIdx.x;
        if (tid < 83200) {
            int b = tid / 5200;
            int r = tid - b * 5200;
            int px = r / 20;
            int ck = (r - px * 20) * 16;
            int row, col;
            if (px < 66)       { row = 0;  col = px; }
            else if (px < 132) { row = 65; col = px - 66; }
            else { int e = px - 132; row = 1 + (e >> 1); col = (e & 1) * 65; }
            size_t off = ((size_t)(b * 66 + row) * 66 + col) * 320 + ck;
            v4i z = {0, 0, 0, 0};
            *(v4i*)&xq[off] = z;
        }
    } else {
        const float step_b = *step_b_p;
        const float xs = 1.0f / *step_x_p;
        const float ws = 1.0f / *step_w_p;
        const float shift = *shift_p;
#pragma unroll
        for (int co = threadIdx.x; co < 320; co += 256) {
            float b_deq = clampf(rintf(bias[co] / step_b), -QMAX, QMAX) * step_b;
            float v = ((b_deq * shift) * xs) * ws;
            bi[co] = clampf(rintf(v), -QMAX, QMAX);
        }
    }
}

// ---------------------------------------------------------------------------
// Implicit-GEMM conv, v_mfma_i32_16x16x64_i8.
// Wave tile: 64co x 128px (2 output rows), acc[4][8].
// Block: WAVES waves -> 64co x (WAVES*2) output rows; B = (ROWS+2) padded rows
// resident, all 9 taps of A resident -> 2 barriers per ci-chunk (10 total).
// ---------------------------------------------------------------------------
template<int ROWS, int WAVES>
__global__ __launch_bounds__(WAVES * 64, 2) void conv_mfma_kernel(
    const char* __restrict__ xq, const char* __restrict__ wq2,
    const float* __restrict__ bi, const float* __restrict__ shift_p,
    float* __restrict__ out)
{
    extern __shared__ __align__(16) char lds[];
    char* B_lds = lds;                              // (ROWS+2)*66*64, swizzled
    char* A_lds = lds + (ROWS + 2) * 66 * 64;       // 9*4*1024 = 36,864

    const int t   = threadIdx.x;
    const int bx  = blockIdx.x;          // co tile 0..4
    const int co0 = bx * 64;
    const int ptile = blockIdx.y;
    constexpr int TPI = 64 / ROWS;       // pixel tiles per image
    const int b  = ptile / TPI;
    const int h0 = (ptile % TPI) * ROWS;

    const int wave = t >> 6, lane = t & 63;
    const int quad = lane >> 4, l15 = lane & 15;

    const char* xbase = xq + ((size_t)(b * 66 + h0) * 66) * 320;
    constexpr int BCHUNKS = (ROWS + 2) * 66 * 4;    // 16B chunks in B tile

    v4i acc[4][8] = {};

    for (int c5 = 0; c5 < 5; ++c5) {
        const int ci0 = c5 * 64;

        // --- stage B (global -> VGPR -> LDS, xor-swizzled) ---
        for (int c = t; c < BCHUNKS; c += WAVES * 64) {
            int px = c >> 2;
            int ck = (c & 3) << 4;
            v4i v = *(const v4i*)&xbase[(size_t)px * 320 + ci0 + ck];
            *(v4i*)&B_lds[px * 64 + (ck ^ ((((px >> 1) & 3)) << 4))] = v;
        }
        // --- stage A: 9 taps x 4 cog, 1KB DMA segments ---
        for (int seg = wave; seg < 36; seg += WAVES) {
            int p = seg >> 2, cog = seg & 3;
            const char* g = wq2 + (size_t)p * 102400
                            + ((size_t)(c5 * 20 + bx * 4 + cog)) * 1024
                            + (size_t)lane * 16;
            gload_lds16(g, &A_lds[seg * 1024]);
        }
        __syncthreads();

#pragma unroll
        for (int p = 0; p < 9; ++p) {
            const int dh = p / 3, dw = p - dh * 3;
            v4i a[4];
#pragma unroll
            for (int cs = 0; cs < 4; ++cs)
                a[cs] = *(const v4i*)&A_lds[(p * 4 + cs) * 1024 + lane * 16];
#pragma unroll
            for (int half = 0; half < 2; ++half) {
                const int prow = wave * 2 + half + dh;   // padded row (local)
#pragma unroll
                for (int i = 0; i < 4; ++i) {
                    const int px = prow * 66 + i * 16 + l15 + dw;
                    v4i bf = *(const v4i*)&B_lds[px * 64 +
                              ((quad << 4) ^ ((((px >> 1) & 3)) << 4))];
#pragma unroll
                    for (int cs = 0; cs < 4; ++cs)
                        acc[cs][half * 4 + i] = mfma_i8(a[cs], bf, acc[cs][half * 4 + i]);
                }
            }
        }
        __syncthreads();
    }

    // epilogue: y_shift = clip(rint(y*shift)); out = clip(y_shift + b_int8)
    const float shift = *shift_p;
#pragma unroll
    for (int cs = 0; cs < 4; ++cs) {
#pragma unroll
        for (int reg = 0; reg < 4; ++reg) {
            const int co = co0 + cs * 16 + quad * 4 + reg;
            const float bv = bi[co];
#pragma unroll
            for (int half = 0; half < 2; ++half) {
                const int h = h0 + wave * 2 + half;
                float* orow = out + (((size_t)(b * 320 + co) * 64) + h) * 64;
#pragma unroll
                for (int i = 0; i < 4; ++i) {
                    float y  = (float)acc[cs][half * 4 + i][reg];
                    float ys = clampf(rintf(y * shift), -QMAX, QMAX);
                    orow[i * 16 + l15] = clampf(ys + bv, -QMAX, QMAX);
                }
            }
        }
    }
}

extern "C" void kernel_launch(void* const* d_in, const int* in_sizes, int n_in,
                              void* d_out, int out_size, void* d_ws, size_t ws_size,
                              hipStream_t stream) {
    const float* x      = (const float*)d_in[0];
    const float* w      = (const float*)d_in[1];
    const float* bias   = (const float*)d_in[2];
    const float* step_x = (const float*)d_in[3];
    const float* step_w = (const float*)d_in[4];
    const float* step_b = (const float*)d_in[5];
    const float* shift  = (const float*)d_in[6];
    float* out = (float*)d_out;

    char*  xq  = (char*)d_ws;
    char*  wq2 = xq + XQ_BYTES;
    float* bi  = (float*)(wq2 + WQ_BYTES);

    quant_x_kernel<<<dim3(5, 64, 16), 256, 0, stream>>>(x, step_x, xq);
    prep_kernel<<<3926, 256, 0, stream>>>(w, bias, step_w, step_b, step_x, shift,
                                          wq2, xq, bi);

    // Preferred: 4-wave / 8-row blocks, 79,104 B dynamic LDS (needs attribute).
    const int lds_big = (8 + 2) * 66 * 64 + 36864;   // 79,104
    hipError_t e = hipFuncSetAttribute(
        reinterpret_cast<const void*>(&conv_mfma_kernel<8, 4>),
        hipFuncAttributeMaxDynamicSharedMemorySize, lds_big);
    if (e == hipSuccess) {
        conv_mfma_kernel<8, 4><<<dim3(5, 128), 256, lds_big, stream>>>(
            xq, wq2, bi, shift, out);
    } else {
        (void)hipGetLastError();   // clear sticky error
        const int lds_small = (4 + 2) * 66 * 64 + 36864;   // 62,208 (< 64 KB)
        conv_mfma_kernel<4, 2><<<dim3(5, 256), 128, lds_small, stream>>>(
            xq, wq2, bi, shift, out);
    }
}